// Round 8
// baseline (100.645 us; speedup 1.0000x reference)
//
#include <hip/hip_runtime.h>
#include <stdint.h>

// W4 group-quantized linear, v7: SPLITK=2 + stage-level B prefetch + wide cvt.
//  * Verified math (v3..v6): biased-nibble MFMA B (bf16 0x4300|n == 128+n exact),
//    k-perm sigma=[0,4,1,5,2,6,3,7] on both A (at cvt) and B (free),
//    per-group fold x.W = s*gacc - s*(128+z)*xsum (rounded-bf16 row sums).
//  * gemm: grid (172,2) = 344 blocks, 256 thr = 4 waves, wave tile M32xN32,
//    K=2048/block in 8 stages of 256 (32KB A LDS each). 1376 waves; lost TLP
//    vs SPLITK=4 is covered by prefetching all 16 B-dwords per stage (ILP).
//  * NO device fences in hot path (v5 lesson: __threadfence = L2 wb/inv on
//    gfx950, ~135us for 688 blocks). Separate reduce dispatch.

#define IN 4096
#define OUT 11008
#define BATCH 64
#define SPLITK 2
#define KSPL 2048
#define BN 64
#define GRID_N 172

typedef __attribute__((ext_vector_type(8))) __bf16 bf16x8;
typedef __attribute__((ext_vector_type(4))) float f32x4;

static __device__ __forceinline__ ushort f2bf(float f) {
  uint32_t u = __float_as_uint(f);
  u += 0x7fff + ((u >> 16) & 1); // RNE
  return (ushort)(u >> 16);
}
static __device__ __forceinline__ float bf2f(ushort h) {
  return __uint_as_float(((uint32_t)h) << 16);
}

// 128 blocks x 64 thr: block = (group g, m-quarter mq). Thread t: local row
// m_local = t>>2, k-quarter q = t&3 (32 consecutive k). Emits xbf in
// A-frag-major kperm order + exact xsum[g][m] via shfl (no atomics).
__global__ void cvt_frag_kernel(const float* __restrict__ x,
                                ushort* __restrict__ xbf,
                                float* __restrict__ xsum) {
  const int g = blockIdx.x >> 2;
  const int mq = blockIdx.x & 3;
  const int t = threadIdx.x;
  const int m = mq * 16 + (t >> 2);
  const int q = t & 3;
  const int ks = 4 * g + q; // 32-wide k slab
  const int kb = 32 * ks;

  float v[32];
  ushort vb[32];
  float s = 0.f;
#pragma unroll
  for (int c4 = 0; c4 < 8; ++c4) {
    float4 f = *(const float4*)&x[m * IN + kb + 4 * c4];
    v[4 * c4 + 0] = f.x; v[4 * c4 + 1] = f.y; v[4 * c4 + 2] = f.z; v[4 * c4 + 3] = f.w;
  }
#pragma unroll
  for (int c = 0; c < 32; ++c) {
    vb[c] = f2bf(v[c]);
    s += bf2f(vb[c]);
  }
  const int i = m >> 4, mlane = m & 15;
#pragma unroll
  for (int qd = 0; qd < 4; ++qd) {
    ushort o[8];
    o[0] = vb[8 * qd + 0]; o[1] = vb[8 * qd + 4];
    o[2] = vb[8 * qd + 1]; o[3] = vb[8 * qd + 5];
    o[4] = vb[8 * qd + 2]; o[5] = vb[8 * qd + 6];
    o[6] = vb[8 * qd + 3]; o[7] = vb[8 * qd + 7];
    const int flat = (ks * 4 + i) * 64 + qd * 16 + mlane;
    *(uint4*)&xbf[flat * 8] = *(uint4*)o;
  }
  s += __shfl_xor(s, 1);
  s += __shfl_xor(s, 2);
  if (q == 0) xsum[g * 64 + m] = s;
}

__global__ __launch_bounds__(256, 3) void mpq_gemm(
    const ushort* __restrict__ xbf,    // frag-major A
    const int* __restrict__ qweight,   // [512][11008]
    const float* __restrict__ scales,  // [32][11008]
    const float* __restrict__ zeros,   // [32][11008]
    const float* __restrict__ xsum,    // [32][64]
    float* __restrict__ P)             // [2][64][11008] partials
{
  __shared__ uint4 A_lds[2048]; // 32 KB: [ksl 0..7][i 0..3][lane]

  const int n0 = blockIdx.x * BN;
  const int sp = blockIdx.y;
  const int k0 = sp * KSPL;
  const int tid = threadIdx.x;
  const int lane = tid & 63;
  const int w = tid >> 6;
  const int wm = w >> 1, wn = w & 1;     // M half / N half
  const int mlane = lane & 15, quad = lane >> 4;
  const int ncol = n0 + 32 * wn + mlane; // col base (j adds 16j)

  f32x4 macc[2][2] = {};

  const uint4* gA = (const uint4*)xbf + (size_t)(k0 / 32) * 256;

  for (int h = 0; h < 8; ++h) {
    // ---- B prefetch for the whole stage (16 dwords in flight) ----
    uint32_t q[8][2];
    const int qrow0 = k0 / 8 + h * 32;
#pragma unroll
    for (int ks = 0; ks < 8; ++ks)
#pragma unroll
      for (int j = 0; j < 2; ++j)
        q[ks][j] = (uint32_t)qweight[(size_t)(qrow0 + ks * 4 + quad) * OUT + ncol + 16 * j];

    __syncthreads(); // previous stage's A reads complete
    const uint4* src = gA + (size_t)h * 2048;
#pragma unroll
    for (int it = 0; it < 8; ++it)
      A_lds[tid + 256 * it] = src[tid + 256 * it];
    __syncthreads();

#pragma unroll
    for (int g2 = 0; g2 < 2; ++g2) {
      f32x4 gacc[2][2] = {};
#pragma unroll
      for (int ksl = 0; ksl < 4; ++ksl) {
        const int ks = g2 * 4 + ksl;
        bf16x8 af[2];
#pragma unroll
        for (int i2 = 0; i2 < 2; ++i2)
          af[i2] = *(const bf16x8*)&A_lds[(ks * 4 + 2 * wm + i2) * 64 + lane];
#pragma unroll
        for (int j = 0; j < 2; ++j) {
          uint32_t p[4];
          p[0] = ( q[ks][j]        & 0x000F000Fu) | 0x43004300u;
          p[1] = ((q[ks][j] >>  4) & 0x000F000Fu) | 0x43004300u;
          p[2] = ((q[ks][j] >>  8) & 0x000F000Fu) | 0x43004300u;
          p[3] = ((q[ks][j] >> 12) & 0x000F000Fu) | 0x43004300u;
          bf16x8 bfr = *(bf16x8*)p;
#pragma unroll
          for (int i2 = 0; i2 < 2; ++i2)
            gacc[i2][j] = __builtin_amdgcn_mfma_f32_16x16x32_bf16(af[i2], bfr, gacc[i2][j], 0, 0, 0);
        }
      }
      // fold group: macc += s*gacc - s*(128+z)*rowsum
      const int g = (k0 >> 7) + h * 2 + g2;
      float Sv[2][4];
#pragma unroll
      for (int i2 = 0; i2 < 2; ++i2)
#pragma unroll
        for (int r = 0; r < 4; ++r)
          Sv[i2][r] = xsum[g * 64 + 32 * wm + 16 * i2 + 4 * quad + r];
#pragma unroll
      for (int j = 0; j < 2; ++j) {
        const float s = scales[g * OUT + ncol + 16 * j];
        const float z = zeros[g * OUT + ncol + 16 * j];
        const float u = s * (128.0f + z);
#pragma unroll
        for (int i2 = 0; i2 < 2; ++i2)
#pragma unroll
          for (int r = 0; r < 4; ++r)
            macc[i2][j][r] = fmaf(s, gacc[i2][j][r], fmaf(-u, Sv[i2][r], macc[i2][j][r]));
      }
    }
  }

  // partial stores (coalesced 64B per quad-row)
  float* Pp = P + (size_t)sp * (BATCH * OUT);
#pragma unroll
  for (int i2 = 0; i2 < 2; ++i2)
#pragma unroll
    for (int r = 0; r < 4; ++r) {
      const int m = 32 * wm + 16 * i2 + 4 * quad + r;
#pragma unroll
      for (int j = 0; j < 2; ++j)
        Pp[(size_t)m * OUT + ncol + 16 * j] = macc[i2][j][r];
    }
}

__global__ void reduce_kernel(const float* __restrict__ P, float* __restrict__ out) {
  const int t = blockIdx.x * blockDim.x + threadIdx.x; // 176128 float4-slots
  float4 a = ((const float4*)P)[t];
#pragma unroll
  for (int s = 1; s < SPLITK; ++s) {
    float4 b = ((const float4*)P)[t + (size_t)s * (BATCH * OUT / 4)];
    a.x += b.x; a.y += b.y; a.z += b.z; a.w += b.w;
  }
  ((float4*)out)[t] = a;
}

extern "C" void kernel_launch(void* const* d_in, const int* in_sizes, int n_in,
                              void* d_out, int out_size, void* d_ws, size_t ws_size,
                              hipStream_t stream) {
  const float* x = (const float*)d_in[0];
  const int* qweight = (const int*)d_in[1];
  const float* scales = (const float*)d_in[2];
  const float* zeros = (const float*)d_in[3];
  float* out = (float*)d_out;
  ushort* xbf = (ushort*)d_ws;                      // 512 KB, frag-major
  float* xsum = (float*)((char*)d_ws + (1 << 19));  // 8 KB
  float* P = (float*)((char*)d_ws + (1 << 20));     // 5.6 MB partials

  cvt_frag_kernel<<<128, 64, 0, stream>>>(x, xbf, xsum);
  mpq_gemm<<<dim3(GRID_N, SPLITK), 256, 0, stream>>>(xbf, qweight, scales, zeros, xsum, P);
  reduce_kernel<<<BATCH * OUT / 4 / 256, 256, 0, stream>>>(P, out);
}

// Round 9
// 93.502 us; speedup vs baseline: 1.0764x; 1.0764x over previous
//
#include <hip/hip_runtime.h>
#include <hip/hip_fp16.h>
#include <stdint.h>

// W4 group-quantized linear, v8: R7 structure (SPLITK=4, 2752 waves) +
// stage-level B prefetch (ILP on top of TLP) + f16 partials (halved P traffic).
//  * R8 lesson: TLP (2.7 waves/SIMD) is the latency-hiding mechanism; prefetch
//    alone at 1.34 waves/SIMD regressed +5.7us. Keep SPLITK=4.
//  * v5 lesson: no device fences in hot path (L2 wb/inv on gfx950).
//  * Verified math: biased-nibble MFMA B (bf16 0x4300|n == 128+n exact),
//    k-perm sigma=[0,4,1,5,2,6,3,7] on both A (at cvt) and B (free),
//    per-group fold x.W = s*gacc - s*(128+z)*xsum (rounded-bf16 row sums).

#define IN 4096
#define OUT 11008
#define BATCH 64
#define SPLITK 4
#define KSPL 1024
#define BN 64
#define GRID_N 172

typedef __attribute__((ext_vector_type(8))) __bf16 bf16x8;
typedef __attribute__((ext_vector_type(4))) float f32x4;

static __device__ __forceinline__ ushort f2bf(float f) {
  uint32_t u = __float_as_uint(f);
  u += 0x7fff + ((u >> 16) & 1); // RNE
  return (ushort)(u >> 16);
}
static __device__ __forceinline__ float bf2f(ushort h) {
  return __uint_as_float(((uint32_t)h) << 16);
}

// 128 blocks x 64 thr: block = (group g, m-quarter mq). Thread t: local row
// m = mq*16 + (t>>2), k-quarter q = t&3 (32 consecutive k). Emits xbf in
// A-frag-major kperm order + exact xsum[g][m] via shfl (no atomics).
__global__ void cvt_frag_kernel(const float* __restrict__ x,
                                ushort* __restrict__ xbf,
                                float* __restrict__ xsum) {
  const int g = blockIdx.x >> 2;
  const int mq = blockIdx.x & 3;
  const int t = threadIdx.x;
  const int m = mq * 16 + (t >> 2);
  const int q = t & 3;
  const int ks = 4 * g + q; // 32-wide k slab
  const int kb = 32 * ks;

  float v[32];
  ushort vb[32];
  float s = 0.f;
#pragma unroll
  for (int c4 = 0; c4 < 8; ++c4) {
    float4 f = *(const float4*)&x[m * IN + kb + 4 * c4];
    v[4 * c4 + 0] = f.x; v[4 * c4 + 1] = f.y; v[4 * c4 + 2] = f.z; v[4 * c4 + 3] = f.w;
  }
#pragma unroll
  for (int c = 0; c < 32; ++c) {
    vb[c] = f2bf(v[c]);
    s += bf2f(vb[c]);
  }
  const int i = m >> 4, mlane = m & 15;
#pragma unroll
  for (int qd = 0; qd < 4; ++qd) {
    ushort o[8];
    o[0] = vb[8 * qd + 0]; o[1] = vb[8 * qd + 4];
    o[2] = vb[8 * qd + 1]; o[3] = vb[8 * qd + 5];
    o[4] = vb[8 * qd + 2]; o[5] = vb[8 * qd + 6];
    o[6] = vb[8 * qd + 3]; o[7] = vb[8 * qd + 7];
    const int flat = (ks * 4 + i) * 64 + qd * 16 + mlane;
    *(uint4*)&xbf[flat * 8] = *(uint4*)o;
  }
  s += __shfl_xor(s, 1);
  s += __shfl_xor(s, 2);
  if (q == 0) xsum[g * 64 + m] = s;
}

__global__ __launch_bounds__(256, 3) void mpq_gemm(
    const ushort* __restrict__ xbf,    // frag-major A
    const int* __restrict__ qweight,   // [512][11008]
    const float* __restrict__ scales,  // [32][11008]
    const float* __restrict__ zeros,   // [32][11008]
    const float* __restrict__ xsum,    // [32][64]
    __half* __restrict__ P)            // [4][64][11008] f16 partials
{
  __shared__ uint4 A_lds[2048]; // 32 KB: [ksl 0..7][i 0..3][lane]

  const int n0 = blockIdx.x * BN;
  const int sp = blockIdx.y;
  const int k0 = sp * KSPL;
  const int tid = threadIdx.x;
  const int lane = tid & 63;
  const int w = tid >> 6;
  const int wm = w >> 1, wn = w & 1;     // M half / N half
  const int mlane = lane & 15, quad = lane >> 4;
  const int ncol = n0 + 32 * wn + mlane; // col base (j adds 16j)

  f32x4 macc[2][2] = {};

  const uint4* gA = (const uint4*)xbf + (size_t)(k0 / 32) * 256;

  for (int h = 0; h < 4; ++h) {
    // ---- B prefetch for the whole stage (16 dwords in flight, overlaps
    //      the barrier + A staging; TLP at 2.7 waves/SIMD does the rest) ----
    uint32_t q[8][2];
    const int qrow0 = k0 / 8 + h * 32;
#pragma unroll
    for (int ks = 0; ks < 8; ++ks)
#pragma unroll
      for (int j = 0; j < 2; ++j)
        q[ks][j] = (uint32_t)qweight[(size_t)(qrow0 + ks * 4 + quad) * OUT + ncol + 16 * j];

    __syncthreads(); // previous stage's A reads complete
    const uint4* src = gA + (size_t)h * 2048;
#pragma unroll
    for (int it = 0; it < 8; ++it)
      A_lds[tid + 256 * it] = src[tid + 256 * it];
    __syncthreads();

#pragma unroll
    for (int g2 = 0; g2 < 2; ++g2) {
      f32x4 gacc[2][2] = {};
#pragma unroll
      for (int ksl = 0; ksl < 4; ++ksl) {
        const int ks = g2 * 4 + ksl;
        bf16x8 af[2];
#pragma unroll
        for (int i2 = 0; i2 < 2; ++i2)
          af[i2] = *(const bf16x8*)&A_lds[(ks * 4 + 2 * wm + i2) * 64 + lane];
#pragma unroll
        for (int j = 0; j < 2; ++j) {
          uint32_t p[4];
          p[0] = ( q[ks][j]        & 0x000F000Fu) | 0x43004300u;
          p[1] = ((q[ks][j] >>  4) & 0x000F000Fu) | 0x43004300u;
          p[2] = ((q[ks][j] >>  8) & 0x000F000Fu) | 0x43004300u;
          p[3] = ((q[ks][j] >> 12) & 0x000F000Fu) | 0x43004300u;
          bf16x8 bfr = *(bf16x8*)p;
#pragma unroll
          for (int i2 = 0; i2 < 2; ++i2)
            gacc[i2][j] = __builtin_amdgcn_mfma_f32_16x16x32_bf16(af[i2], bfr, gacc[i2][j], 0, 0, 0);
        }
      }
      // fold group: macc += s*gacc - s*(128+z)*rowsum
      const int g = (k0 >> 7) + h * 2 + g2;
      float Sv[2][4];
#pragma unroll
      for (int i2 = 0; i2 < 2; ++i2)
#pragma unroll
        for (int r = 0; r < 4; ++r)
          Sv[i2][r] = xsum[g * 64 + 32 * wm + 16 * i2 + 4 * quad + r];
#pragma unroll
      for (int j = 0; j < 2; ++j) {
        const float s = scales[g * OUT + ncol + 16 * j];
        const float z = zeros[g * OUT + ncol + 16 * j];
        const float u = s * (128.0f + z);
#pragma unroll
        for (int i2 = 0; i2 < 2; ++i2)
#pragma unroll
          for (int r = 0; r < 4; ++r)
            macc[i2][j][r] = fmaf(s, gacc[i2][j][r], fmaf(-u, Sv[i2][r], macc[i2][j][r]));
      }
    }
  }

  // f16 partial stores (partials ~ +-5, f16 ulp ~0.004 -> negligible error)
  __half* Pp = P + (size_t)sp * (BATCH * OUT);
#pragma unroll
  for (int i2 = 0; i2 < 2; ++i2)
#pragma unroll
    for (int r = 0; r < 4; ++r) {
      const int m = 32 * wm + 16 * i2 + 4 * quad + r;
#pragma unroll
      for (int j = 0; j < 2; ++j)
        Pp[(size_t)m * OUT + ncol + 16 * j] = __float2half(macc[i2][j][r]);
    }
}

__global__ void reduce_kernel(const __half* __restrict__ P, float* __restrict__ out) {
  const int t = blockIdx.x * blockDim.x + threadIdx.x; // 176128 4-elem slots
  float4 a = {0.f, 0.f, 0.f, 0.f};
  const uint2* P2 = (const uint2*)P; // 4 halves per uint2
#pragma unroll
  for (int s = 0; s < SPLITK; ++s) {
    uint2 v = P2[t + (size_t)s * (BATCH * OUT / 4)];
    const __half2 lo = *(const __half2*)&v.x;
    const __half2 hi = *(const __half2*)&v.y;
    float2 flo = __half22float2(lo), fhi = __half22float2(hi);
    a.x += flo.x; a.y += flo.y; a.z += fhi.x; a.w += fhi.y;
  }
  ((float4*)out)[t] = a;
}

extern "C" void kernel_launch(void* const* d_in, const int* in_sizes, int n_in,
                              void* d_out, int out_size, void* d_ws, size_t ws_size,
                              hipStream_t stream) {
  const float* x = (const float*)d_in[0];
  const int* qweight = (const int*)d_in[1];
  const float* scales = (const float*)d_in[2];
  const float* zeros = (const float*)d_in[3];
  float* out = (float*)d_out;
  ushort* xbf = (ushort*)d_ws;                      // 512 KB, frag-major
  float* xsum = (float*)((char*)d_ws + (1 << 19));  // 8 KB
  __half* P = (__half*)((char*)d_ws + (1 << 20));   // 5.6 MB f16 partials

  cvt_frag_kernel<<<128, 64, 0, stream>>>(x, xbf, xsum);
  mpq_gemm<<<dim3(GRID_N, SPLITK), 256, 0, stream>>>(xbf, qweight, scales, zeros, xsum, P);
  reduce_kernel<<<BATCH * OUT / 4 / 256, 256, 0, stream>>>(P, out);
}